// Round 2
// baseline (798.487 us; speedup 1.0000x reference)
//
#include <hip/hip_runtime.h>
#include <math.h>

#define T_TOK 65536
#define K_CODE 1024
#define E_DIM 64
#define DECAYF 0.99f
#define EPSF 1e-5f

// --- exact-rounding helpers: block ffp-contract=fast fusion ---
__device__ __forceinline__ float mul_nf(float a, float b) {
#pragma clang fp contract(off)
    return a * b;
}
__device__ __forceinline__ float add_nf(float a, float b) {
#pragma clang fp contract(off)
    return a + b;
}
__device__ __forceinline__ float sub_nf(float a, float b) {
#pragma clang fp contract(off)
    return a - b;
}

// numpy pairwise_sum for n=64 contiguous fp32 of elementwise squares:
// p[i] = fl(v[i]*v[i]) (separate rounding, no fma), then 8 strided
// accumulators r[j] += p[i+j], combined ((r0+r1)+(r2+r3))+((r4+r5)+(r6+r7)).
__device__ __forceinline__ float np_sq_sum64(const float* v) {
    float p[64];
#pragma unroll
    for (int i = 0; i < 64; ++i) p[i] = mul_nf(v[i], v[i]);
    float r[8];
#pragma unroll
    for (int j = 0; j < 8; ++j) r[j] = p[j];
#pragma unroll
    for (int i = 8; i < 64; i += 8) {
#pragma unroll
        for (int j = 0; j < 8; ++j) r[j] = add_nf(r[j], p[i + j]);
    }
    float s01 = add_nf(r[0], r[1]);
    float s23 = add_nf(r[2], r[3]);
    float s45 = add_nf(r[4], r[5]);
    float s67 = add_nf(r[6], r[7]);
    return add_nf(add_nf(s01, s23), add_nf(s45, s67));
}

// ws layout (floats):
// [0, 65536)       embed_sum accumulator (1024 x 64)
// [65536, 66560)   onehot counts (1024)
// [66560]          diff accumulator
// [66561, 67585)   wnorm (1024)

__global__ __launch_bounds__(256) void wnorm_kernel(const float* __restrict__ embed,
                                                    float* __restrict__ wnorm) {
    int k = blockIdx.x * 256 + threadIdx.x;
    if (k < K_CODE) {
        float w[64];
        const float4* wp = reinterpret_cast<const float4*>(embed + (size_t)k * E_DIM);
#pragma unroll
        for (int i = 0; i < 16; ++i) {
            float4 v = wp[i];
            w[4 * i + 0] = v.x; w[4 * i + 1] = v.y; w[4 * i + 2] = v.z; w[4 * i + 3] = v.w;
        }
        wnorm[k] = np_sq_sum64(w);
    }
}

__global__ __launch_bounds__(256) void argmin_kernel(const float* __restrict__ z_e,
                                                     const float* __restrict__ embed,
                                                     const float* __restrict__ wnorm,
                                                     float* __restrict__ out_zq,
                                                     float* __restrict__ out_ind,
                                                     float* __restrict__ diff_acc) {
    int t = blockIdx.x * 256 + threadIdx.x;

    // token vector in registers
    float x[64];
    const float4* xp = reinterpret_cast<const float4*>(z_e + (size_t)t * E_DIM);
#pragma unroll
    for (int i = 0; i < 16; ++i) {
        float4 v = xp[i];
        x[4 * i + 0] = v.x; x[4 * i + 1] = v.y; x[4 * i + 2] = v.z; x[4 * i + 3] = v.w;
    }

    // numpy-exact ||x||^2
    float xn = np_sq_sum64(x);

    float best = INFINITY;
    int idx = 0;

    // sgemm emulation: sequential-k FMA chain per dot product.
    // k-unroll x2: two independent chains for latency hiding; compare order
    // preserved (k then k+1) so first-min semantics match np.argmin.
    for (int k = 0; k < K_CODE; k += 2) {
        const float* w0 = embed + (size_t)k * E_DIM;
        const float* w1 = w0 + E_DIM;
        float d0 = 0.f, d1 = 0.f;
#pragma unroll
        for (int i = 0; i < 64; ++i) {
            d0 = __builtin_fmaf(x[i], w0[i], d0);
            d1 = __builtin_fmaf(x[i], w1[i], d1);
        }
        // dist = (xnorm - 2*mm) + wnorm, elementwise fp32, one rounding per op
        float m0 = d0 + d0;  // exact (x2)
        float m1 = d1 + d1;
        float t0 = sub_nf(xn, m0);
        float t1 = sub_nf(xn, m1);
        float dist0 = add_nf(t0, wnorm[k]);
        float dist1 = add_nf(t1, wnorm[k + 1]);
        if (dist0 < best) { best = dist0; idx = k; }
        if (dist1 < best) { best = dist1; idx = k + 1; }
    }

    out_ind[t] = (float)idx;

    // z_q gather + straight-through output + diff partial
    // np order: r = fl(z_q - z_e); out = fl(z_e + r)
    const float4* wq = reinterpret_cast<const float4*>(embed + (size_t)idx * E_DIM);
    float4* oz = reinterpret_cast<float4*>(out_zq + (size_t)t * E_DIM);
    float ds = 0.f;
#pragma unroll
    for (int i = 0; i < 16; ++i) {
        float4 w4 = wq[i];
        float rx = sub_nf(w4.x, x[4 * i + 0]);
        float ry = sub_nf(w4.y, x[4 * i + 1]);
        float rz = sub_nf(w4.z, x[4 * i + 2]);
        float rw = sub_nf(w4.w, x[4 * i + 3]);
        float4 o;
        o.x = add_nf(x[4 * i + 0], rx);
        o.y = add_nf(x[4 * i + 1], ry);
        o.z = add_nf(x[4 * i + 2], rz);
        o.w = add_nf(x[4 * i + 3], rw);
        oz[i] = o;
        ds = __builtin_fmaf(rx, rx, ds);
        ds = __builtin_fmaf(ry, ry, ds);
        ds = __builtin_fmaf(rz, rz, ds);
        ds = __builtin_fmaf(rw, rw, ds);
    }

    __shared__ float red[256];
    red[threadIdx.x] = ds;
    __syncthreads();
#pragma unroll
    for (int s = 128; s > 0; s >>= 1) {
        if (threadIdx.x < s) red[threadIdx.x] += red[threadIdx.x + s];
        __syncthreads();
    }
    if (threadIdx.x == 0) atomicAdd(diff_acc, red[0]);
}

__global__ __launch_bounds__(256) void scatter_kernel(const float* __restrict__ z_e,
                                                      const float* __restrict__ out_ind,
                                                      float* __restrict__ embed_sum,
                                                      float* __restrict__ onehot) {
    int lane = threadIdx.x & 63;
    int wid = threadIdx.x >> 6;
    int t0 = (blockIdx.x * 4 + wid) * 64;
    for (int j = 0; j < 64; ++j) {
        int t = t0 + j;
        int idx = (int)out_ind[t];  // wave-uniform
        float v = z_e[(size_t)t * E_DIM + lane];
        atomicAdd(&embed_sum[(size_t)idx * E_DIM + lane], v);
        if (lane == 0) atomicAdd(&onehot[idx], 1.0f);
    }
}

__global__ __launch_bounds__(1024) void finalize_kernel(const float* __restrict__ cluster_size,
                                                        const float* __restrict__ embed_avg,
                                                        const float* __restrict__ ws_esum,
                                                        const float* __restrict__ ws_onehot,
                                                        const float* __restrict__ ws_diff,
                                                        float* __restrict__ out_diff,
                                                        float* __restrict__ out_ne,
                                                        float* __restrict__ out_ncs,
                                                        float* __restrict__ out_nea) {
    int k = threadIdx.x;
    float ncs = DECAYF * cluster_size[k] + (1.0f - DECAYF) * ws_onehot[k];

    __shared__ float red[1024];
    red[k] = ncs;
    __syncthreads();
#pragma unroll
    for (int s = 512; s > 0; s >>= 1) {
        if (k < s) red[k] += red[k + s];
        __syncthreads();
    }
    float n = red[0];

    float cs = (ncs + EPSF) / (n + (float)K_CODE * EPSF) * n;
    out_ncs[k] = ncs;

    const float4* ea = reinterpret_cast<const float4*>(embed_avg + (size_t)k * E_DIM);
    const float4* es = reinterpret_cast<const float4*>(ws_esum + (size_t)k * E_DIM);
    float4* one = reinterpret_cast<float4*>(out_ne + (size_t)k * E_DIM);
    float4* onea = reinterpret_cast<float4*>(out_nea + (size_t)k * E_DIM);
#pragma unroll
    for (int i = 0; i < 16; ++i) {
        float4 a = ea[i], s4 = es[i], nea, ne;
        nea.x = DECAYF * a.x + (1.0f - DECAYF) * s4.x;
        nea.y = DECAYF * a.y + (1.0f - DECAYF) * s4.y;
        nea.z = DECAYF * a.z + (1.0f - DECAYF) * s4.z;
        nea.w = DECAYF * a.w + (1.0f - DECAYF) * s4.w;
        ne.x = nea.x / cs; ne.y = nea.y / cs; ne.z = nea.z / cs; ne.w = nea.w / cs;
        onea[i] = nea;
        one[i] = ne;
    }
    if (k == 0) out_diff[0] = ws_diff[0] * (1.0f / 4194304.0f);  // /2^22 exact
}

extern "C" void kernel_launch(void* const* d_in, const int* in_sizes, int n_in,
                              void* d_out, int out_size, void* d_ws, size_t ws_size,
                              hipStream_t stream) {
    const float* z_e = (const float*)d_in[0];
    const float* embed = (const float*)d_in[1];
    const float* cluster_size = (const float*)d_in[2];
    const float* embed_avg = (const float*)d_in[3];

    float* out = (float*)d_out;
    float* o_zq = out;                   // 4194304
    float* o_diff = out + 4194304;       // 1
    float* o_ind = out + 4194305;        // 65536
    float* o_ne = out + 4194305 + 65536; // 65536
    float* o_ncs = o_ne + 65536;         // 1024
    float* o_nea = o_ncs + 1024;         // 65536

    float* ws = (float*)d_ws;
    float* ws_esum = ws;            // 65536
    float* ws_onehot = ws + 65536;  // 1024
    float* ws_diff = ws + 66560;    // 1
    float* ws_wnorm = ws + 66561;   // 1024

    hipMemsetAsync(d_ws, 0, (size_t)(65536 + 1024 + 1) * sizeof(float), stream);
    wnorm_kernel<<<4, 256, 0, stream>>>(embed, ws_wnorm);
    argmin_kernel<<<256, 256, 0, stream>>>(z_e, embed, ws_wnorm, o_zq, o_ind, ws_diff);
    scatter_kernel<<<256, 256, 0, stream>>>(z_e, o_ind, ws_esum, ws_onehot);
    finalize_kernel<<<1, 1024, 0, stream>>>(cluster_size, embed_avg, ws_esum, ws_onehot,
                                            ws_diff, o_diff, o_ne, o_ncs, o_nea);
}

// Round 3
// 722.248 us; speedup vs baseline: 1.1056x; 1.1056x over previous
//
#include <hip/hip_runtime.h>
#include <math.h>

#define T_TOK 65536
#define K_CODE 1024
#define E_DIM 64
#define DECAYF 0.99f
#define EPSF 1e-5f

// --- exact-rounding helpers: block ffp-contract=fast fusion ---
__device__ __forceinline__ float mul_nf(float a, float b) {
#pragma clang fp contract(off)
    return a * b;
}
__device__ __forceinline__ float add_nf(float a, float b) {
#pragma clang fp contract(off)
    return a + b;
}
__device__ __forceinline__ float sub_nf(float a, float b) {
#pragma clang fp contract(off)
    return a - b;
}

// numpy pairwise_sum for n=64 of elementwise squares: products rounded
// separately (no fma), 8 strided accumulators, fixed combine tree.
// Rewritten without the p[64] temp (same rounding order, less VGPR pressure).
__device__ __forceinline__ float np_sq_sum64(const float* v) {
    float r[8];
#pragma unroll
    for (int j = 0; j < 8; ++j) r[j] = mul_nf(v[j], v[j]);
#pragma unroll
    for (int i = 8; i < 64; i += 8) {
#pragma unroll
        for (int j = 0; j < 8; ++j) r[j] = add_nf(r[j], mul_nf(v[i + j], v[i + j]));
    }
    float s01 = add_nf(r[0], r[1]);
    float s23 = add_nf(r[2], r[3]);
    float s45 = add_nf(r[4], r[5]);
    float s67 = add_nf(r[6], r[7]);
    return add_nf(add_nf(s01, s23), add_nf(s45, s67));
}

// ws layout (floats):
// [0, 65536)       embed_sum accumulator (1024 x 64)
// [65536, 66560)   onehot counts (1024)
// [66560]          diff accumulator
// [66561, 67585)   wnorm (1024)

__global__ __launch_bounds__(256) void wnorm_kernel(const float* __restrict__ embed,
                                                    float* __restrict__ wnorm) {
    int k = blockIdx.x * 256 + threadIdx.x;
    if (k < K_CODE) {
        float w[64];
        const float4* wp = reinterpret_cast<const float4*>(embed + (size_t)k * E_DIM);
#pragma unroll
        for (int i = 0; i < 16; ++i) {
            float4 v = wp[i];
            w[4 * i + 0] = v.x; w[4 * i + 1] = v.y; w[4 * i + 2] = v.z; w[4 * i + 3] = v.w;
        }
        wnorm[k] = np_sq_sum64(w);
    }
}

// Block = 256 threads = 4 waves. Each block owns 64 tokens (= lane id);
// wave w scans code segment [w*256, (w+1)*256). Per-(token,code) distance
// arithmetic identical to the verified round-2 kernel => bit-exact vs np.
// Segment results combined in LDS; strict < keeps np.argmin first-min
// semantics (higher segments always have larger indices).
__global__ __launch_bounds__(256, 4) void argmin_kernel(const float* __restrict__ z_e,
                                                        const float* __restrict__ embed,
                                                        const float* __restrict__ wnorm,
                                                        float* __restrict__ out_zq,
                                                        float* __restrict__ out_ind,
                                                        float* __restrict__ diff_acc) {
    int lane = threadIdx.x & 63;
    int wave = threadIdx.x >> 6;
    int t = blockIdx.x * 64 + lane;

    // token vector in registers
    float x[64];
    const float4* xp = reinterpret_cast<const float4*>(z_e + (size_t)t * E_DIM);
#pragma unroll
    for (int i = 0; i < 16; ++i) {
        float4 v = xp[i];
        x[4 * i + 0] = v.x; x[4 * i + 1] = v.y; x[4 * i + 2] = v.z; x[4 * i + 3] = v.w;
    }

    // numpy-exact ||x||^2
    float xn = np_sq_sum64(x);

    float best = INFINITY;
    int idx = wave << 8;

    for (int k = (wave << 8); k < (wave << 8) + 256; k += 2) {
        const float* w0 = embed + (size_t)k * E_DIM;
        const float* w1 = w0 + E_DIM;
        float d0 = 0.f, d1 = 0.f;
#pragma unroll
        for (int i = 0; i < 64; ++i) {
            d0 = __builtin_fmaf(x[i], w0[i], d0);
            d1 = __builtin_fmaf(x[i], w1[i], d1);
        }
        float m0 = d0 + d0;  // exact (x2)
        float m1 = d1 + d1;
        float dist0 = add_nf(sub_nf(xn, m0), wnorm[k]);
        float dist1 = add_nf(sub_nf(xn, m1), wnorm[k + 1]);
        if (dist0 < best) { best = dist0; idx = k; }
        if (dist1 < best) { best = dist1; idx = k + 1; }
    }

    __shared__ float sd[4][64];
    __shared__ int si[4][64];
    sd[wave][lane] = best;
    si[wave][lane] = idx;
    __syncthreads();

    if (wave == 0) {
        float b = sd[0][lane];
        int bi = si[0][lane];
#pragma unroll
        for (int w = 1; w < 4; ++w) {
            float d = sd[w][lane];
            int i2 = si[w][lane];
            if (d < b) { b = d; bi = i2; }  // ties keep lower segment = np first-min
        }
        out_ind[t] = (float)bi;

        // z_q gather + straight-through output + diff partial
        // np order: r = fl(z_q - z_e); out = fl(z_e + r)
        const float4* wq = reinterpret_cast<const float4*>(embed + (size_t)bi * E_DIM);
        float4* oz = reinterpret_cast<float4*>(out_zq + (size_t)t * E_DIM);
        float ds = 0.f;
#pragma unroll
        for (int i = 0; i < 16; ++i) {
            float4 w4 = wq[i];
            float rx = sub_nf(w4.x, x[4 * i + 0]);
            float ry = sub_nf(w4.y, x[4 * i + 1]);
            float rz = sub_nf(w4.z, x[4 * i + 2]);
            float rw = sub_nf(w4.w, x[4 * i + 3]);
            float4 o;
            o.x = add_nf(x[4 * i + 0], rx);
            o.y = add_nf(x[4 * i + 1], ry);
            o.z = add_nf(x[4 * i + 2], rz);
            o.w = add_nf(x[4 * i + 3], rw);
            oz[i] = o;
            ds = __builtin_fmaf(rx, rx, ds);
            ds = __builtin_fmaf(ry, ry, ds);
            ds = __builtin_fmaf(rz, rz, ds);
            ds = __builtin_fmaf(rw, rw, ds);
        }
#pragma unroll
        for (int o = 32; o > 0; o >>= 1) ds += __shfl_down(ds, o, 64);
        if (lane == 0) atomicAdd(diff_acc, ds);
    }
}

__global__ __launch_bounds__(256) void scatter_kernel(const float* __restrict__ z_e,
                                                      const float* __restrict__ out_ind,
                                                      float* __restrict__ embed_sum,
                                                      float* __restrict__ onehot) {
    int lane = threadIdx.x & 63;
    int wid = threadIdx.x >> 6;
    int t0 = (blockIdx.x * 4 + wid) * 16;
    for (int j = 0; j < 16; ++j) {
        int t = t0 + j;
        int idx = (int)out_ind[t];  // wave-uniform
        float v = z_e[(size_t)t * E_DIM + lane];
        atomicAdd(&embed_sum[(size_t)idx * E_DIM + lane], v);
        if (lane == 0) atomicAdd(&onehot[idx], 1.0f);
    }
}

__global__ __launch_bounds__(1024) void finalize_kernel(const float* __restrict__ cluster_size,
                                                        const float* __restrict__ embed_avg,
                                                        const float* __restrict__ ws_esum,
                                                        const float* __restrict__ ws_onehot,
                                                        const float* __restrict__ ws_diff,
                                                        float* __restrict__ out_diff,
                                                        float* __restrict__ out_ne,
                                                        float* __restrict__ out_ncs,
                                                        float* __restrict__ out_nea) {
    int k = threadIdx.x;
    float ncs = DECAYF * cluster_size[k] + (1.0f - DECAYF) * ws_onehot[k];

    __shared__ float red[1024];
    red[k] = ncs;
    __syncthreads();
#pragma unroll
    for (int s = 512; s > 0; s >>= 1) {
        if (k < s) red[k] += red[k + s];
        __syncthreads();
    }
    float n = red[0];

    float cs = (ncs + EPSF) / (n + (float)K_CODE * EPSF) * n;
    out_ncs[k] = ncs;

    const float4* ea = reinterpret_cast<const float4*>(embed_avg + (size_t)k * E_DIM);
    const float4* es = reinterpret_cast<const float4*>(ws_esum + (size_t)k * E_DIM);
    float4* one = reinterpret_cast<float4*>(out_ne + (size_t)k * E_DIM);
    float4* onea = reinterpret_cast<float4*>(out_nea + (size_t)k * E_DIM);
#pragma unroll
    for (int i = 0; i < 16; ++i) {
        float4 a = ea[i], s4 = es[i], nea, ne;
        nea.x = DECAYF * a.x + (1.0f - DECAYF) * s4.x;
        nea.y = DECAYF * a.y + (1.0f - DECAYF) * s4.y;
        nea.z = DECAYF * a.z + (1.0f - DECAYF) * s4.z;
        nea.w = DECAYF * a.w + (1.0f - DECAYF) * s4.w;
        ne.x = nea.x / cs; ne.y = nea.y / cs; ne.z = nea.z / cs; ne.w = nea.w / cs;
        onea[i] = nea;
        one[i] = ne;
    }
    if (k == 0) out_diff[0] = ws_diff[0] * (1.0f / 4194304.0f);  // /2^22 exact
}

extern "C" void kernel_launch(void* const* d_in, const int* in_sizes, int n_in,
                              void* d_out, int out_size, void* d_ws, size_t ws_size,
                              hipStream_t stream) {
    const float* z_e = (const float*)d_in[0];
    const float* embed = (const float*)d_in[1];
    const float* cluster_size = (const float*)d_in[2];
    const float* embed_avg = (const float*)d_in[3];

    float* out = (float*)d_out;
    float* o_zq = out;                   // 4194304
    float* o_diff = out + 4194304;       // 1
    float* o_ind = out + 4194305;        // 65536
    float* o_ne = out + 4194305 + 65536; // 65536
    float* o_ncs = o_ne + 65536;         // 1024
    float* o_nea = o_ncs + 1024;         // 65536

    float* ws = (float*)d_ws;
    float* ws_esum = ws;            // 65536
    float* ws_onehot = ws + 65536;  // 1024
    float* ws_diff = ws + 66560;    // 1
    float* ws_wnorm = ws + 66561;   // 1024

    hipMemsetAsync(d_ws, 0, (size_t)(65536 + 1024 + 1) * sizeof(float), stream);
    wnorm_kernel<<<4, 256, 0, stream>>>(embed, ws_wnorm);
    argmin_kernel<<<1024, 256, 0, stream>>>(z_e, embed, ws_wnorm, o_zq, o_ind, ws_diff);
    scatter_kernel<<<1024, 256, 0, stream>>>(z_e, o_ind, ws_esum, ws_onehot);
    finalize_kernel<<<1, 1024, 0, stream>>>(cluster_size, embed_avg, ws_esum, ws_onehot,
                                            ws_diff, o_diff, o_ne, o_ncs, o_nea);
}